// Round 1
// baseline (464.153 us; speedup 1.0000x reference)
//
#include <hip/hip_runtime.h>
#include <cstdint>
#include <cstddef>

typedef unsigned short u16;
typedef __bf16 bf16x8 __attribute__((ext_vector_type(8)));
typedef float f32x4 __attribute__((ext_vector_type(4)));

#define B_ 4
#define T_ 2048
#define E_ 1024
#define H_ 16
#define D_ 64
#define HD3_ 3072
#define M_ (B_*T_)

__device__ __forceinline__ u16 f2bf(float f) {
  union { float f; unsigned u; } v; v.f = f;
  unsigned r = v.u + 0x7FFFu + ((v.u >> 16) & 1u);
  return (u16)(r >> 16);
}

__device__ __forceinline__ void gl2lds16(const u16* g, u16* l) {
  __builtin_amdgcn_global_load_lds(
      (const __attribute__((address_space(1))) unsigned int*)g,
      (__attribute__((address_space(3))) unsigned int*)l, 16, 0, 0);
}

// ---------------- prep: x -> bf16 ----------------
__global__ void prep_x(const float* __restrict__ x, u16* __restrict__ xb) {
  const long n4 = (long)(M_) * E_ / 4;
  for (long i = (long)blockIdx.x * blockDim.x + threadIdx.x; i < n4;
       i += (long)gridDim.x * blockDim.x) {
    float4 v = ((const float4*)x)[i];
    unsigned lo = (unsigned)f2bf(v.x) | ((unsigned)f2bf(v.y) << 16);
    unsigned hi = (unsigned)f2bf(v.z) | ((unsigned)f2bf(v.w) << 16);
    ((uint2*)xb)[i] = make_uint2(lo, hi);
  }
}

// ---------------- prep: weights -> bf16, transposed to [N][K] ----------------
// WT[n][e], n in [0,3072): n<1024 Wq, <2048 Wk, else Wv; within: h=(n%1024)/64, d=n%64
// WcT[n][k] = Wc[k][n]
__global__ void prep_w(const float* __restrict__ Wq, const float* __restrict__ Wk,
                       const float* __restrict__ Wv, const float* __restrict__ Wc,
                       u16* __restrict__ WT, u16* __restrict__ WcT) {
  const int total = HD3_ * E_ + E_ * E_;
  for (int i = blockIdx.x * blockDim.x + threadIdx.x; i < total;
       i += gridDim.x * blockDim.x) {
    if (i < HD3_ * E_) {
      int n = i >> 10, e = i & 1023;
      int mtx = n >> 10, hd = n & 1023, h = hd >> 6, d = hd & 63;
      const float* W = (mtx == 0) ? Wq : (mtx == 1) ? Wk : Wv;
      WT[i] = f2bf(W[((size_t)h * E_ + e) * D_ + d]);
    } else {
      int j = i - HD3_ * E_;
      int n = j >> 10, k = j & 1023;
      WcT[j] = f2bf(Wc[(size_t)k * E_ + n]);
    }
  }
}

// ---------------- GEMM: C[M][ldc] = A[M][K](bf16) * Bt[N][K]^T ----------------
// 128x128 tile, BK=32, 4 waves (2x2), 16x16x32 bf16 MFMA (m97 structure)
template<bool OUT_BF16>
__global__ __launch_bounds__(256) void gemm_bt(
    const u16* __restrict__ A, const u16* __restrict__ Bt,
    void* __restrict__ Cv, int K, int ldc)
{
  __shared__ u16 As[128 * 32];
  __shared__ u16 Bs[128 * 32];
  const int tid = threadIdx.x;
  const int lane = tid & 63, w = tid >> 6;
  const int wr = (w >> 1) * 64, wc = (w & 1) * 64;
  const int lrow = lane & 15, lk8 = (lane >> 4) * 8;
  const long bm = (long)blockIdx.y * 128;
  const long bn = (long)blockIdx.x * 128;
  f32x4 acc[4][4] = {};

  for (int k0 = 0; k0 < K; k0 += 32) {
    __syncthreads();
#pragma unroll
    for (int i = 0; i < 2; ++i) {
      int c = i * 256 + tid, r = c >> 2, cc = c & 3;
      gl2lds16(A + (size_t)(bm + r) * K + k0 + cc * 8, &As[c * 8]);
    }
#pragma unroll
    for (int i = 0; i < 2; ++i) {
      int c = i * 256 + tid, r = c >> 2, cc = c & 3;
      gl2lds16(Bt + (size_t)(bn + r) * K + k0 + cc * 8, &Bs[c * 8]);
    }
    __syncthreads();
    bf16x8 af[4], bfr[4];
#pragma unroll
    for (int mi = 0; mi < 4; ++mi)
      af[mi] = *(const bf16x8*)&As[(wr + mi * 16 + lrow) * 32 + lk8];
#pragma unroll
    for (int ni = 0; ni < 4; ++ni)
      bfr[ni] = *(const bf16x8*)&Bs[(wc + ni * 16 + lrow) * 32 + lk8];
#pragma unroll
    for (int mi = 0; mi < 4; ++mi)
#pragma unroll
      for (int ni = 0; ni < 4; ++ni)
        acc[mi][ni] = __builtin_amdgcn_mfma_f32_16x16x32_bf16(
            af[mi], bfr[ni], acc[mi][ni], 0, 0, 0);
  }

#pragma unroll
  for (int mi = 0; mi < 4; ++mi)
#pragma unroll
    for (int ni = 0; ni < 4; ++ni) {
      long row = bm + wr + mi * 16 + (lane >> 4) * 4;
      long col = bn + wc + ni * 16 + lrow;
#pragma unroll
      for (int j = 0; j < 4; ++j) {
        if (OUT_BF16)
          ((u16*)Cv)[(size_t)(row + j) * ldc + col] = f2bf(acc[mi][ni][j]);
        else
          ((float*)Cv)[(size_t)(row + j) * ldc + col] = acc[mi][ni][j];
      }
    }
}

// ---------------- V transpose: QKV V-part [B,T,H,D] -> VT[B*H][D][T] ----------------
__global__ __launch_bounds__(256) void transpose_v(const u16* __restrict__ QKV,
                                                   u16* __restrict__ VT) {
  const int bh = blockIdx.y, b = bh >> 4, h = bh & 15;
  const int t0 = blockIdx.x * 64;
  __shared__ u16 tile[64][72];
  const int tid = threadIdx.x;
  const u16* src = QKV + ((size_t)(b * T_ + t0) * HD3_ + 2048 + h * 64);
#pragma unroll
  for (int i = 0; i < 2; ++i) {
    int c = i * 256 + tid;
    int r = c >> 3, cc = (c & 7) * 8;
    uint4 v = *(const uint4*)(src + (size_t)r * HD3_ + cc);
    *(uint4*)&tile[r][cc] = v;
  }
  __syncthreads();
  u16* dst = VT + (size_t)bh * D_ * T_ + t0;
#pragma unroll
  for (int i = 0; i < 16; ++i) {
    int idx = i * 256 + tid;
    int d = idx >> 6, tl = idx & 63;
    dst[(size_t)d * T_ + tl] = tile[tl][d];
  }
}

// ---------------- flash attention (causal) ----------------
// grid (32, 64): x = q-tile (reversed for heavy-first), y = b*H+h
// block 256 = 4 waves, each wave 16 q-rows; QBLK=KBLK=64
__global__ __launch_bounds__(256) void attn_kernel(
    const u16* __restrict__ QKV, const u16* __restrict__ VT,
    u16* __restrict__ O)
{
  const int bh = blockIdx.y, b = bh >> 4, h = bh & 15;
  const int qt = (int)gridDim.x - 1 - (int)blockIdx.x;
  const int q0 = qt * 64;
  const int tid = threadIdx.x, w = tid >> 6, lane = tid & 63;
  const int lrow = lane & 15, g = lane >> 4;

  __shared__ u16 Qs[64 * 64], Ks[64 * 64], Vs[64 * 64];
  __shared__ u16 Ps[4][16 * 64];

  const u16* Qg = QKV + ((size_t)(b * T_ + q0) * HD3_ + h * 64);
  const u16* Kg = QKV + ((size_t)(b * T_) * HD3_ + 1024 + h * 64);
  const u16* Vg = VT + (size_t)bh * D_ * T_;

  // stage Q (swizzled source so LDS is linear but reads are conflict-free)
#pragma unroll
  for (int i = 0; i < 2; ++i) {
    int c = i * 256 + tid, r = c >> 3, cc = c & 7;
    int sc = cc ^ (r & 7);
    gl2lds16(Qg + (size_t)r * HD3_ + sc * 8, &Qs[c * 8]);
  }

  f32x4 acc[4] = {};
  float mrun[4], lrun[4];
#pragma unroll
  for (int j = 0; j < 4; ++j) { mrun[j] = -1e30f; lrun[j] = 0.f; }

  for (int kt = 0; kt <= qt; ++kt) {
    const int kv0 = kt * 64;
    __syncthreads();  // previous iteration's LDS reads complete
#pragma unroll
    for (int i = 0; i < 2; ++i) {
      int c = i * 256 + tid, r = c >> 3, cc = c & 7;
      int sc = cc ^ (r & 7);
      gl2lds16(Kg + (size_t)(kv0 + r) * HD3_ + sc * 8, &Ks[c * 8]);
    }
#pragma unroll
    for (int i = 0; i < 2; ++i) {
      int c = i * 256 + tid, r = c >> 3, cc = c & 7;
      int sc = cc ^ (r & 7);
      gl2lds16(Vg + (size_t)r * T_ + kv0 + sc * 8, &Vs[c * 8]);
    }
    __syncthreads();  // staged data visible (vmcnt drained by barrier)

    // ---- S = Q K^T (one 16-row m-frag per wave, 4 n-frags, K=64 => 2 MFMA steps)
    f32x4 s[4] = {};
    bf16x8 aq[2];
#pragma unroll
    for (int kk = 0; kk < 2; ++kk) {
      int row = w * 16 + lrow;
      int ch = (kk * 4 + g) ^ (row & 7);
      aq[kk] = *(const bf16x8*)&Qs[row * 64 + ch * 8];
    }
#pragma unroll
    for (int ni = 0; ni < 4; ++ni)
#pragma unroll
      for (int kk = 0; kk < 2; ++kk) {
        int row = ni * 16 + lrow;
        int ch = (kk * 4 + g) ^ (row & 7);
        bf16x8 bk = *(const bf16x8*)&Ks[row * 64 + ch * 8];
        s[ni] = __builtin_amdgcn_mfma_f32_16x16x32_bf16(aq[kk], bk, s[ni], 0, 0, 0);
      }

    // ---- scale + causal mask + online softmax
    float pv[4][4];
#pragma unroll
    for (int j = 0; j < 4; ++j) {
      int qrow = q0 + w * 16 + g * 4 + j;
      float mx = -1e30f;
#pragma unroll
      for (int ni = 0; ni < 4; ++ni) {
        float v = s[ni][j] * 0.125f;
        int kg = kv0 + ni * 16 + lrow;
        if (kt == qt && kg > qrow) v = -1e30f;
        s[ni][j] = v;
        mx = fmaxf(mx, v);
      }
#pragma unroll
      for (int mk = 1; mk < 16; mk <<= 1) mx = fmaxf(mx, __shfl_xor(mx, mk, 64));
      float mnew = fmaxf(mrun[j], mx);
      float corr = __expf(mrun[j] - mnew);
      float sum = 0.f;
#pragma unroll
      for (int ni = 0; ni < 4; ++ni) {
        float p = __expf(s[ni][j] - mnew);
        pv[ni][j] = p; sum += p;
      }
#pragma unroll
      for (int mk = 1; mk < 16; mk <<= 1) sum += __shfl_xor(sum, mk, 64);
      lrun[j] = lrun[j] * corr + sum;
      mrun[j] = mnew;
#pragma unroll
      for (int ni = 0; ni < 4; ++ni) acc[ni][j] *= corr;
    }

    // ---- P -> per-wave LDS (swizzled) to get MFMA A-frag layout
#pragma unroll
    for (int j = 0; j < 4; ++j) {
      int row = g * 4 + j;
#pragma unroll
      for (int ni = 0; ni < 4; ++ni) {
        int col = ni * 16 + lrow;
        int ch = (col >> 3) ^ (row & 7);
        Ps[w][row * 64 + ch * 8 + (col & 7)] = f2bf(pv[ni][j]);
      }
    }

    // ---- O += P V   (A = P [16][64], B^T = VT tile [d][kt])
    bf16x8 ap[2];
#pragma unroll
    for (int kk = 0; kk < 2; ++kk) {
      int ch = (kk * 4 + g) ^ (lrow & 7);
      ap[kk] = *(const bf16x8*)&Ps[w][lrow * 64 + ch * 8];
    }
#pragma unroll
    for (int ni = 0; ni < 4; ++ni)
#pragma unroll
      for (int kk = 0; kk < 2; ++kk) {
        int row = ni * 16 + lrow;
        int ch = (kk * 4 + g) ^ (row & 7);
        bf16x8 bv = *(const bf16x8*)&Vs[row * 64 + ch * 8];
        acc[ni] = __builtin_amdgcn_mfma_f32_16x16x32_bf16(ap[kk], bv, acc[ni], 0, 0, 0);
      }
  }

  // ---- epilogue: normalize, store bf16 [B,T,H,D]
  u16* Og = O + ((size_t)(b * T_ + q0 + w * 16) * (H_ * D_) + h * 64);
#pragma unroll
  for (int j = 0; j < 4; ++j) {
    float inv = 1.f / lrun[j];
    int row = g * 4 + j;
#pragma unroll
    for (int ni = 0; ni < 4; ++ni)
      Og[(size_t)row * (H_ * D_) + ni * 16 + lrow] = f2bf(acc[ni][j] * inv);
  }
}

// ---------------- launch ----------------
extern "C" void kernel_launch(void* const* d_in, const int* in_sizes, int n_in,
                              void* d_out, int out_size, void* d_ws, size_t ws_size,
                              hipStream_t stream) {
  const float* x  = (const float*)d_in[0];
  const float* Wq = (const float*)d_in[1];
  const float* Wk = (const float*)d_in[2];
  const float* Wv = (const float*)d_in[3];
  const float* Wc = (const float*)d_in[4];

  char* ws = (char*)d_ws;
  u16* xb  = (u16*)(ws);                    // 16.8 MB [8192][1024]
  u16* WT  = (u16*)(ws + 16777216);         // 6.3 MB  [3072][1024]
  u16* WcT = (u16*)(ws + 23068672);         // 2.1 MB  [1024][1024]
  u16* QKV = (u16*)(ws + 25165824);         // 50.3 MB [8192][3072]
  u16* Ob  = (u16*)(ws + 75497472);         // 16.8 MB [8192][1024]
  u16* VT  = xb;                            // reuse xb after proj GEMM (16.8 MB)
  float* out = (float*)d_out;

  prep_x<<<2048, 256, 0, stream>>>(x, xb);
  prep_w<<<4096, 256, 0, stream>>>(Wq, Wk, Wv, Wc, WT, WcT);
  // QKV projection: M=8192, N=3072, K=1024
  gemm_bt<true><<<dim3(24, 64), 256, 0, stream>>>(xb, WT, QKV, 1024, 3072);
  transpose_v<<<dim3(32, 64), 256, 0, stream>>>(QKV, VT);
  attn_kernel<<<dim3(32, 64), 256, 0, stream>>>(QKV, VT, Ob);
  // output projection: M=8192, N=1024, K=1024
  gemm_bt<false><<<dim3(8, 64), 256, 0, stream>>>(Ob, WcT, out, 1024, 1024);
}

// Round 2
// 280.186 us; speedup vs baseline: 1.6566x; 1.6566x over previous
//
#include <hip/hip_runtime.h>
#include <cstdint>
#include <cstddef>

typedef unsigned short u16;
typedef __bf16 bf16x8 __attribute__((ext_vector_type(8)));
typedef float f32x4 __attribute__((ext_vector_type(4)));
typedef float f32x16 __attribute__((ext_vector_type(16)));

#define B_ 4
#define T_ 2048
#define E_ 1024
#define H_ 16
#define D_ 64
#define HD3_ 3072
#define M_ (B_*T_)

__device__ __forceinline__ u16 f2bf(float f) {
  union { float f; unsigned u; } v; v.f = f;
  unsigned r = v.u + 0x7FFFu + ((v.u >> 16) & 1u);
  return (u16)(r >> 16);
}

__device__ __forceinline__ unsigned cvtpk(float a, float b) {
  unsigned r;
  asm("v_cvt_pk_bf16_f32 %0, %1, %2" : "=v"(r) : "v"(a), "v"(b));
  return r;
}

__device__ __forceinline__ void gl2lds16(const u16* g, u16* l) {
  __builtin_amdgcn_global_load_lds(
      (const __attribute__((address_space(1))) unsigned int*)g,
      (__attribute__((address_space(3))) unsigned int*)l, 16, 0, 0);
}

// ---------------- prep: x -> bf16 ----------------
__global__ void prep_x(const float* __restrict__ x, u16* __restrict__ xb) {
  const long n4 = (long)(M_) * E_ / 4;
  for (long i = (long)blockIdx.x * blockDim.x + threadIdx.x; i < n4;
       i += (long)gridDim.x * blockDim.x) {
    float4 v = ((const float4*)x)[i];
    unsigned lo = (unsigned)f2bf(v.x) | ((unsigned)f2bf(v.y) << 16);
    unsigned hi = (unsigned)f2bf(v.z) | ((unsigned)f2bf(v.w) << 16);
    ((uint2*)xb)[i] = make_uint2(lo, hi);
  }
}

// ---------------- prep: weights -> bf16, transposed to [N][K] ----------------
__global__ void prep_w(const float* __restrict__ Wq, const float* __restrict__ Wk,
                       const float* __restrict__ Wv, const float* __restrict__ Wc,
                       u16* __restrict__ WT, u16* __restrict__ WcT) {
  const int total = HD3_ * E_ + E_ * E_;
  for (int i = blockIdx.x * blockDim.x + threadIdx.x; i < total;
       i += gridDim.x * blockDim.x) {
    if (i < HD3_ * E_) {
      int n = i >> 10, e = i & 1023;
      int mtx = n >> 10, hd = n & 1023, h = hd >> 6, d = hd & 63;
      const float* W = (mtx == 0) ? Wq : (mtx == 1) ? Wk : Wv;
      WT[i] = f2bf(W[((size_t)h * E_ + e) * D_ + d]);
    } else {
      int j = i - HD3_ * E_;
      int n = j >> 10, k = j & 1023;
      WcT[j] = f2bf(Wc[(size_t)k * E_ + n]);
    }
  }
}

// ---------------- GEMM: C[M][ldc] = A[M][K](bf16) * Bt[N][K]^T ----------------
// 128x128 tile, BK=32, 4 waves (2x2), 16x16x32 bf16 MFMA + XCD swizzle
template<bool OUT_BF16>
__global__ __launch_bounds__(256) void gemm_bt(
    const u16* __restrict__ A, const u16* __restrict__ Bt,
    void* __restrict__ Cv, int K, int ldc, int qcols, float qscale)
{
  __shared__ u16 As[128 * 32];
  __shared__ u16 Bs[128 * 32];
  const int tid = threadIdx.x;
  const int lane = tid & 63, w = tid >> 6;
  const int wr = (w >> 1) * 64, wc = (w & 1) * 64;
  const int lrow = lane & 15, lk8 = (lane >> 4) * 8;
  // XCD-aware swizzle (nwg % 8 == 0 for all our launches)
  int lin = blockIdx.y * gridDim.x + blockIdx.x;
  int cpx = (gridDim.x * gridDim.y) >> 3;
  int swz = (lin & 7) * cpx + (lin >> 3);
  int bxi = swz % gridDim.x, byi = swz / gridDim.x;
  const long bm = (long)byi * 128;
  const long bn = (long)bxi * 128;
  f32x4 acc[4][4] = {};

  for (int k0 = 0; k0 < K; k0 += 32) {
    __syncthreads();
#pragma unroll
    for (int i = 0; i < 2; ++i) {
      int c = i * 256 + tid, r = c >> 2, cc = c & 3;
      gl2lds16(A + (size_t)(bm + r) * K + k0 + cc * 8, &As[c * 8]);
    }
#pragma unroll
    for (int i = 0; i < 2; ++i) {
      int c = i * 256 + tid, r = c >> 2, cc = c & 3;
      gl2lds16(Bt + (size_t)(bn + r) * K + k0 + cc * 8, &Bs[c * 8]);
    }
    __syncthreads();
    bf16x8 af[4], bfr[4];
#pragma unroll
    for (int mi = 0; mi < 4; ++mi)
      af[mi] = *(const bf16x8*)&As[(wr + mi * 16 + lrow) * 32 + lk8];
#pragma unroll
    for (int ni = 0; ni < 4; ++ni)
      bfr[ni] = *(const bf16x8*)&Bs[(wc + ni * 16 + lrow) * 32 + lk8];
#pragma unroll
    for (int mi = 0; mi < 4; ++mi)
#pragma unroll
      for (int ni = 0; ni < 4; ++ni)
        acc[mi][ni] = __builtin_amdgcn_mfma_f32_16x16x32_bf16(
            af[mi], bfr[ni], acc[mi][ni], 0, 0, 0);
  }

#pragma unroll
  for (int mi = 0; mi < 4; ++mi)
#pragma unroll
    for (int ni = 0; ni < 4; ++ni) {
      long row = bm + wr + mi * 16 + (lane >> 4) * 4;
      long col = bn + wc + ni * 16 + lrow;
      float sc = (col < qcols) ? qscale : 1.0f;
#pragma unroll
      for (int j = 0; j < 4; ++j) {
        if (OUT_BF16)
          ((u16*)Cv)[(size_t)(row + j) * ldc + col] = f2bf(acc[mi][ni][j] * sc);
        else
          ((float*)Cv)[(size_t)(row + j) * ldc + col] = acc[mi][ni][j];
      }
    }
}

// ---------------- V transpose: QKV V-part [B,T,H,D] -> VT[B*H][D][T] ----------------
__global__ __launch_bounds__(256) void transpose_v(const u16* __restrict__ QKV,
                                                   u16* __restrict__ VT) {
  const int bh = blockIdx.y, b = bh >> 4, h = bh & 15;
  const int t0 = blockIdx.x * 64;
  __shared__ u16 tile[64][72];
  const int tid = threadIdx.x;
  const u16* src = QKV + ((size_t)(b * T_ + t0) * HD3_ + 2048 + h * 64);
#pragma unroll
  for (int i = 0; i < 2; ++i) {
    int c = i * 256 + tid;
    int r = c >> 3, cc = (c & 7) * 8;
    uint4 v = *(const uint4*)(src + (size_t)r * HD3_ + cc);
    *(uint4*)&tile[r][cc] = v;
  }
  __syncthreads();
  u16* dst = VT + (size_t)bh * D_ * T_ + t0;
#pragma unroll
  for (int i = 0; i < 16; ++i) {
    int idx = i * 256 + tid;
    int d = idx >> 6, tl = idx & 63;
    dst[(size_t)d * T_ + tl] = tile[tl][d];
  }
}

// ---------------- flash attention (causal), swapped-QK 32x32 structure ----------------
// grid 1024: bh = L & 63 (XCD = bh%8), qt = 15 - (L>>6) heavy-first
// block 256 = 4 waves, each wave 32 q-rows; QBLK=128, KVBLK=64
// Q pre-scaled by 0.125*log2(e) -> softmax in exp2 domain
__global__ __launch_bounds__(256, 2) void attn_kernel(
    const u16* __restrict__ QKV, const u16* __restrict__ VT,
    u16* __restrict__ O)
{
  __shared__ u16 Ks[2][4096];
  __shared__ u16 Vs[2][4096];
  const int L = blockIdx.x;
  const int bh = L & 63, b = bh >> 4, h = bh & 15;
  const int qt = 15 - (L >> 6);
  const int q0 = qt * 128;
  const int tid = threadIdx.x, w = tid >> 6, lane = tid & 63;
  const int ql = lane & 31, hi = lane >> 5;
  const int qw0 = q0 + w * 32;

  const u16* Qg = QKV + ((size_t)(b * T_ + q0) * HD3_ + h * 64);
  const u16* Kg = QKV + ((size_t)(b * T_) * HD3_ + 1024 + h * 64);
  const u16* Vg = VT + (size_t)bh * (D_ * T_);

  // stage Q [128][64] (swizzled source, linear LDS) into Ks region
#pragma unroll
  for (int i = 0; i < 4; ++i) {
    int c = i * 256 + tid, r = c >> 3, cc = c & 7, sc = cc ^ (r & 7);
    gl2lds16(Qg + (size_t)r * HD3_ + sc * 8, &Ks[0][0] + c * 8);
  }
  __syncthreads();
  bf16x8 qf[4];
  {
    int qrow = w * 32 + ql;
#pragma unroll
    for (int s = 0; s < 4; ++s) {
      int ch = (2 * s + hi) ^ (qrow & 7);
      qf[s] = *(const bf16x8*)(&Ks[0][0] + qrow * 64 + ch * 8);
    }
  }
  __syncthreads();  // all waves done reading Q before Ks[0] is overwritten

  // stage tile 0
#pragma unroll
  for (int i = 0; i < 2; ++i) {
    int c = i * 256 + tid, r = c >> 3, cc = c & 7, sc = cc ^ (r & 7);
    gl2lds16(Kg + (size_t)r * HD3_ + sc * 8, &Ks[0][0] + c * 8);
    gl2lds16(Vg + (size_t)r * T_ + sc * 8, &Vs[0][0] + c * 8);
  }

  f32x16 acc[2];
#pragma unroll
  for (int ni = 0; ni < 2; ++ni)
#pragma unroll
    for (int r = 0; r < 16; ++r) acc[ni][r] = 0.f;
  float mrun = -1e30f, lrun = 0.f;
  const int ktmax = 2 * qt + 2;

  for (int kt = 0; kt < ktmax; ++kt) {
    const int cur = kt & 1;
    const int kv0 = kt * 64;
    __syncthreads();  // publish buf[cur]; protect buf[cur^1]
    if (kt + 1 < ktmax) {
      const int nkv = kv0 + 64;
#pragma unroll
      for (int i = 0; i < 2; ++i) {
        int c = i * 256 + tid, r = c >> 3, cc = c & 7, sc = cc ^ (r & 7);
        gl2lds16(Kg + (size_t)(nkv + r) * HD3_ + sc * 8, &Ks[cur ^ 1][0] + c * 8);
        gl2lds16(Vg + (size_t)r * T_ + nkv + sc * 8, &Vs[cur ^ 1][0] + c * 8);
      }
    }
    if (kv0 > qw0 + 31) continue;  // this wave fully masked (barriers still met)

    // ---- S^T = K Q^T : lane holds 32 k-values for q = qw0 + ql
    f32x16 st[2];
#pragma unroll
    for (int f = 0; f < 2; ++f)
#pragma unroll
      for (int r = 0; r < 16; ++r) st[f][r] = 0.f;
    __builtin_amdgcn_s_setprio(1);
#pragma unroll
    for (int f = 0; f < 2; ++f) {
      const int krow = f * 32 + ql;
      const int swzr = krow & 7;
#pragma unroll
      for (int s = 0; s < 4; ++s) {
        int ch = (2 * s + hi) ^ swzr;
        bf16x8 kfr = *(const bf16x8*)(&Ks[cur][0] + krow * 64 + ch * 8);
        st[f] = __builtin_amdgcn_mfma_f32_32x32x16_bf16(kfr, qf[s], st[f], 0, 0, 0);
      }
    }
    __builtin_amdgcn_s_setprio(0);

    // ---- causal mask (diagonal tiles only)
    if (kv0 + 63 > qw0) {
      const int qg = qw0 + ql;
#pragma unroll
      for (int f = 0; f < 2; ++f)
#pragma unroll
        for (int r = 0; r < 16; ++r) {
          int kg = kv0 + f * 32 + (r & 3) + 8 * (r >> 2) + 4 * hi;
          if (kg > qg) st[f][r] = -1e30f;
        }
    }

    // ---- online softmax (exp2 domain), defer-max THR=8
    float mt = st[0][0];
#pragma unroll
    for (int f = 0; f < 2; ++f)
#pragma unroll
      for (int r = 0; r < 16; ++r) mt = fmaxf(mt, st[f][r]);
    mt = fmaxf(mt, __shfl_xor(mt, 32, 64));
    if (!__all(mt - mrun <= 8.f)) {
      float mnew = fmaxf(mrun, mt);
      float corr = exp2f(mrun - mnew);
      lrun *= corr;
#pragma unroll
      for (int ni = 0; ni < 2; ++ni)
#pragma unroll
        for (int r = 0; r < 16; ++r) acc[ni][r] *= corr;
      mrun = mnew;
    }
    float sum = 0.f;
#pragma unroll
    for (int f = 0; f < 2; ++f)
#pragma unroll
      for (int r = 0; r < 16; ++r) {
        float p = exp2f(st[f][r] - mrun);
        st[f][r] = p;
        sum += p;
      }
    sum += __shfl_xor(sum, 32, 64);
    lrun += sum;

    // ---- P -> bf16 frags (cvt_pk + permlane32_swap), O^T += V^T P^T
    __builtin_amdgcn_s_setprio(1);
#pragma unroll
    for (int s = 0; s < 4; ++s) {
      const int f = s >> 1, bse = (s & 1) * 8;
      unsigned b0 = cvtpk(st[f][bse + 0], st[f][bse + 1]);
      unsigned b1 = cvtpk(st[f][bse + 2], st[f][bse + 3]);
      unsigned a0 = cvtpk(st[f][bse + 4], st[f][bse + 5]);
      unsigned a1 = cvtpk(st[f][bse + 6], st[f][bse + 7]);
      asm volatile("v_permlane32_swap_b32 %0, %1" : "+v"(b0), "+v"(a0));
      asm volatile("v_permlane32_swap_b32 %0, %1" : "+v"(b1), "+v"(a1));
      union { unsigned u[4]; bf16x8 v; } pa;
      pa.u[0] = b0; pa.u[1] = b1; pa.u[2] = a0; pa.u[3] = a1;
#pragma unroll
      for (int ni = 0; ni < 2; ++ni) {
        int vrow = ni * 32 + ql;
        int ch = (2 * s + hi) ^ (vrow & 7);
        bf16x8 vf = *(const bf16x8*)(&Vs[cur][0] + vrow * 64 + ch * 8);
        acc[ni] = __builtin_amdgcn_mfma_f32_32x32x16_bf16(vf, pa.v, acc[ni], 0, 0, 0);
      }
    }
    __builtin_amdgcn_s_setprio(0);
  }

  // ---- epilogue: O[q][d] = acc^T / lrun, store bf16 pairs
  const int q = q0 + w * 32 + ql;
  u16* Og = O + ((size_t)(b * T_ + q) * (H_ * D_) + h * 64);
  const float inv = 1.f / lrun;
#pragma unroll
  for (int ni = 0; ni < 2; ++ni)
#pragma unroll
    for (int rr = 0; rr < 8; ++rr) {
      const int r0 = rr * 2;
      const int d0 = ((r0 & 3) + 8 * (r0 >> 2)) + 4 * hi + ni * 32;
      unsigned pk = cvtpk(acc[ni][r0] * inv, acc[ni][r0 + 1] * inv);
      *(unsigned*)(Og + d0) = pk;
    }
}

// ---------------- launch ----------------
extern "C" void kernel_launch(void* const* d_in, const int* in_sizes, int n_in,
                              void* d_out, int out_size, void* d_ws, size_t ws_size,
                              hipStream_t stream) {
  const float* x  = (const float*)d_in[0];
  const float* Wq = (const float*)d_in[1];
  const float* Wk = (const float*)d_in[2];
  const float* Wv = (const float*)d_in[3];
  const float* Wc = (const float*)d_in[4];

  char* ws = (char*)d_ws;
  u16* xb  = (u16*)(ws);                    // 16.8 MB [8192][1024]
  u16* WT  = (u16*)(ws + 16777216);         // 6.3 MB  [3072][1024]
  u16* WcT = (u16*)(ws + 23068672);         // 2.1 MB  [1024][1024]
  u16* QKV = (u16*)(ws + 25165824);         // 50.3 MB [8192][3072]
  u16* Ob  = (u16*)(ws + 75497472);         // 16.8 MB [8192][1024]
  u16* VT  = xb;                            // reuse xb after proj GEMM
  float* out = (float*)d_out;

  const float QSCALE = 0.125f * 1.4426950408889634f;  // scale * log2(e)

  prep_x<<<2048, 256, 0, stream>>>(x, xb);
  prep_w<<<4096, 256, 0, stream>>>(Wq, Wk, Wv, Wc, WT, WcT);
  // QKV projection: M=8192, N=3072, K=1024 (Q columns pre-scaled)
  gemm_bt<true><<<dim3(24, 64), 256, 0, stream>>>(xb, WT, QKV, 1024, 3072, 1024, QSCALE);
  transpose_v<<<dim3(32, 64), 256, 0, stream>>>(QKV, VT);
  attn_kernel<<<dim3(1024), 256, 0, stream>>>(QKV, VT, Ob);
  // output projection: M=8192, N=1024, K=1024
  gemm_bt<false><<<dim3(8, 64), 256, 0, stream>>>(Ob, WcT, out, 1024, 1024, 0, 1.0f);
}

// Round 3
// 266.829 us; speedup vs baseline: 1.7395x; 1.0501x over previous
//
#include <hip/hip_runtime.h>
#include <cstdint>
#include <cstddef>

typedef unsigned short u16;
typedef __bf16 bf16x8 __attribute__((ext_vector_type(8)));
typedef float f32x4 __attribute__((ext_vector_type(4)));
typedef float f32x16 __attribute__((ext_vector_type(16)));

#define B_ 4
#define T_ 2048
#define E_ 1024
#define H_ 16
#define D_ 64
#define HD3_ 3072
#define M_ (B_*T_)

__device__ __forceinline__ u16 f2bf(float f) {
  union { float f; unsigned u; } v; v.f = f;
  unsigned r = v.u + 0x7FFFu + ((v.u >> 16) & 1u);
  return (u16)(r >> 16);
}

__device__ __forceinline__ unsigned cvtpk(float a, float b) {
  unsigned r;
  asm("v_cvt_pk_bf16_f32 %0, %1, %2" : "=v"(r) : "v"(a), "v"(b));
  return r;
}

__device__ __forceinline__ void gl2lds16(const u16* g, u16* l) {
  __builtin_amdgcn_global_load_lds(
      (const __attribute__((address_space(1))) unsigned int*)g,
      (__attribute__((address_space(3))) unsigned int*)l, 16, 0, 0);
}

// ---------------- prep: x -> bf16 ----------------
__global__ void prep_x(const float* __restrict__ x, u16* __restrict__ xb) {
  const long n4 = (long)(M_) * E_ / 4;
  for (long i = (long)blockIdx.x * blockDim.x + threadIdx.x; i < n4;
       i += (long)gridDim.x * blockDim.x) {
    float4 v = ((const float4*)x)[i];
    unsigned lo = (unsigned)f2bf(v.x) | ((unsigned)f2bf(v.y) << 16);
    unsigned hi = (unsigned)f2bf(v.z) | ((unsigned)f2bf(v.w) << 16);
    ((uint2*)xb)[i] = make_uint2(lo, hi);
  }
}

// ---------------- prep: weights -> bf16, transposed to [N][K] ----------------
__global__ void prep_w(const float* __restrict__ Wq, const float* __restrict__ Wk,
                       const float* __restrict__ Wv, const float* __restrict__ Wc,
                       u16* __restrict__ WT, u16* __restrict__ WcT) {
  const int total = HD3_ * E_ + E_ * E_;
  for (int i = blockIdx.x * blockDim.x + threadIdx.x; i < total;
       i += gridDim.x * blockDim.x) {
    if (i < HD3_ * E_) {
      int n = i >> 10, e = i & 1023;
      int mtx = n >> 10, hd = n & 1023, h = hd >> 6, d = hd & 63;
      const float* W = (mtx == 0) ? Wq : (mtx == 1) ? Wk : Wv;
      WT[i] = f2bf(W[((size_t)h * E_ + e) * D_ + d]);
    } else {
      int j = i - HD3_ * E_;
      int n = j >> 10, k = j & 1023;
      WcT[j] = f2bf(Wc[(size_t)k * E_ + n]);
    }
  }
}

// ---------------- 8-phase-style GEMM: C[M][N_] = A[M][1024] * Bt[N_][1024]^T ----------------
// tile 128x256, BK=64, NT=16 K-tiles, 512 thr = 8 waves (2M x 4N), per-wave 64x64
// LDS 96KB: As 2x[128][64], Bs 2x[256][64]; XOR-chunk swizzle; counted vmcnt pipeline
template<int N_, bool OUT_BF16>
__global__ __launch_bounds__(512, 2) void gemm8(
    const u16* __restrict__ A, const u16* __restrict__ Bt,
    void* __restrict__ Cv, float qscale)
{
  __shared__ u16 As[2][128 * 64];
  __shared__ u16 Bs[2][256 * 64];
  const int tid = threadIdx.x;
  const int lane = tid & 63, w = tid >> 6;
  const int wr = w >> 2, wc = w & 3;
  const int l15 = lane & 15, l4 = lane >> 4;

  const int gx = N_ / 256;
  const int lin = blockIdx.x;
  const int cpx = (gx * 64) >> 3;
  const int swz = (lin & 7) * cpx + (lin >> 3);
  const int bxi = swz % gx, byi = swz / gx;
  const size_t bm = (size_t)byi * 128, bn = (size_t)bxi * 256;
  const u16* Ag = A + bm * 1024;
  const u16* Bg = Bt + bn * 1024;

  auto stageA = [&](int b, int t, int i) {
    int idx = i * 512 + tid, r = idx >> 3, c = idx & 7;
    gl2lds16(Ag + (size_t)r * 1024 + t * 64 + ((c ^ (r & 7)) * 8), &As[b][idx * 8]);
  };
  auto stageB = [&](int b, int t, int i) {
    int idx = i * 512 + tid, r = idx >> 3, c = idx & 7;
    gl2lds16(Bg + (size_t)r * 1024 + t * 64 + ((c ^ (r & 7)) * 8), &Bs[b][idx * 8]);
  };

  int aoff[4][2], boff[4][2];
#pragma unroll
  for (int m = 0; m < 4; ++m) {
    int r = wr * 64 + m * 16 + l15;
#pragma unroll
    for (int s = 0; s < 2; ++s)
      aoff[m][s] = r * 64 + (((s * 4 + l4) ^ (r & 7)) * 8);
  }
#pragma unroll
  for (int n = 0; n < 4; ++n) {
    int r = wc * 64 + n * 16 + l15;
#pragma unroll
    for (int s = 0; s < 2; ++s)
      boff[n][s] = r * 64 + (((s * 4 + l4) ^ (r & 7)) * 8);
  }

  f32x4 acc[4][4] = {};

  // prologue: tile0 full -> buf0; A(tile1) -> buf1
#pragma unroll
  for (int i = 0; i < 2; ++i) stageA(0, 0, i);
#pragma unroll
  for (int i = 0; i < 4; ++i) stageB(0, 0, i);
#pragma unroll
  for (int i = 0; i < 2; ++i) stageA(1, 1, i);
  asm volatile("s_waitcnt vmcnt(2)" ::: "memory");
  __builtin_amdgcn_s_barrier();

  for (int t = 0; t < 16; ++t) {
    const int cur = t & 1;
    bf16x8 af[4][2], bfv[4][2];
    // ---- P1: read A(all) + B01; stage B012(t+1) -> other buf
#pragma unroll
    for (int m = 0; m < 4; ++m)
#pragma unroll
      for (int s = 0; s < 2; ++s)
        af[m][s] = *(const bf16x8*)&As[cur][aoff[m][s]];
#pragma unroll
    for (int n = 0; n < 2; ++n)
#pragma unroll
      for (int s = 0; s < 2; ++s)
        bfv[n][s] = *(const bf16x8*)&Bs[cur][boff[n][s]];
    if (t + 1 < 16) {
      stageB(cur ^ 1, t + 1, 0);
      stageB(cur ^ 1, t + 1, 1);
      stageB(cur ^ 1, t + 1, 2);
    }
    __builtin_amdgcn_s_barrier();
    asm volatile("s_waitcnt lgkmcnt(0)" ::: "memory");
    __builtin_amdgcn_sched_barrier(0);
    __builtin_amdgcn_s_setprio(1);
#pragma unroll
    for (int m = 0; m < 4; ++m)
#pragma unroll
      for (int n = 0; n < 2; ++n)
#pragma unroll
        for (int s = 0; s < 2; ++s)
          acc[m][n] = __builtin_amdgcn_mfma_f32_16x16x32_bf16(
              af[m][s], bfv[n][s], acc[m][n], 0, 0, 0);
    __builtin_amdgcn_s_setprio(0);
    __builtin_amdgcn_s_barrier();

    // ---- P2: read B23; stage B3(t+1), A01(t+2) (A region of cur consumed)
#pragma unroll
    for (int n = 2; n < 4; ++n)
#pragma unroll
      for (int s = 0; s < 2; ++s)
        bfv[n][s] = *(const bf16x8*)&Bs[cur][boff[n][s]];
    if (t + 1 < 16) stageB(cur ^ 1, t + 1, 3);
    if (t + 2 < 16) { stageA(cur, t + 2, 0); stageA(cur, t + 2, 1); }
    __builtin_amdgcn_s_barrier();
    asm volatile("s_waitcnt lgkmcnt(0)" ::: "memory");
    __builtin_amdgcn_sched_barrier(0);
    __builtin_amdgcn_s_setprio(1);
#pragma unroll
    for (int m = 0; m < 4; ++m)
#pragma unroll
      for (int n = 2; n < 4; ++n)
#pragma unroll
        for (int s = 0; s < 2; ++s)
          acc[m][n] = __builtin_amdgcn_mfma_f32_16x16x32_bf16(
              af[m][s], bfv[n][s], acc[m][n], 0, 0, 0);
    __builtin_amdgcn_s_setprio(0);
    if (t + 2 < 16)      asm volatile("s_waitcnt vmcnt(2)" ::: "memory");
    else if (t + 1 < 16) asm volatile("s_waitcnt vmcnt(0)" ::: "memory");
    __builtin_amdgcn_s_barrier();
  }

  // ---- epilogue
#pragma unroll
  for (int m = 0; m < 4; ++m)
#pragma unroll
    for (int n = 0; n < 4; ++n) {
      size_t row = bm + wr * 64 + m * 16 + l4 * 4;
      size_t col = bn + wc * 64 + n * 16 + l15;
      float sc = (col < 1024) ? qscale : 1.0f;
#pragma unroll
      for (int j = 0; j < 4; ++j) {
        if (OUT_BF16)
          ((u16*)Cv)[(row + j) * N_ + col] = f2bf(acc[m][n][j] * sc);
        else
          ((float*)Cv)[(row + j) * N_ + col] = acc[m][n][j];
      }
    }
}

// ---------------- V transpose: QKV V-part [B,T,H,D] -> VT[B*H][D][T] ----------------
__global__ __launch_bounds__(256) void transpose_v(const u16* __restrict__ QKV,
                                                   u16* __restrict__ VT) {
  const int bh = blockIdx.y, b = bh >> 4, h = bh & 15;
  const int t0 = blockIdx.x * 64;
  __shared__ u16 tile[64][72];
  const int tid = threadIdx.x;
  const u16* src = QKV + ((size_t)(b * T_ + t0) * HD3_ + 2048 + h * 64);
#pragma unroll
  for (int i = 0; i < 2; ++i) {
    int c = i * 256 + tid;
    int r = c >> 3, cc = (c & 7) * 8;
    uint4 v = *(const uint4*)(src + (size_t)r * HD3_ + cc);
    *(uint4*)&tile[r][cc] = v;
  }
  __syncthreads();
  u16* dst = VT + (size_t)bh * D_ * T_ + t0;
#pragma unroll
  for (int i = 0; i < 16; ++i) {
    int idx = i * 256 + tid;
    int d = idx >> 6, tl = idx & 63;
    dst[(size_t)d * T_ + tl] = tile[tl][d];
  }
}

// ---------------- flash attention (causal), swapped-QK 32x32 structure ----------------
__global__ __launch_bounds__(256, 2) void attn_kernel(
    const u16* __restrict__ QKV, const u16* __restrict__ VT,
    u16* __restrict__ O)
{
  __shared__ u16 Ks[2][4096];
  __shared__ u16 Vs[2][4096];
  const int L = blockIdx.x;
  const int bh = L & 63, b = bh >> 4, h = bh & 15;
  const int qt = 15 - (L >> 6);
  const int q0 = qt * 128;
  const int tid = threadIdx.x, w = tid >> 6, lane = tid & 63;
  const int ql = lane & 31, hi = lane >> 5;
  const int qw0 = q0 + w * 32;

  const u16* Qg = QKV + ((size_t)(b * T_ + q0) * HD3_ + h * 64);
  const u16* Kg = QKV + ((size_t)(b * T_) * HD3_ + 1024 + h * 64);
  const u16* Vg = VT + (size_t)bh * (D_ * T_);

#pragma unroll
  for (int i = 0; i < 4; ++i) {
    int c = i * 256 + tid, r = c >> 3, cc = c & 7, sc = cc ^ (r & 7);
    gl2lds16(Qg + (size_t)r * HD3_ + sc * 8, &Ks[0][0] + c * 8);
  }
  __syncthreads();
  bf16x8 qf[4];
  {
    int qrow = w * 32 + ql;
#pragma unroll
    for (int s = 0; s < 4; ++s) {
      int ch = (2 * s + hi) ^ (qrow & 7);
      qf[s] = *(const bf16x8*)(&Ks[0][0] + qrow * 64 + ch * 8);
    }
  }
  __syncthreads();

#pragma unroll
  for (int i = 0; i < 2; ++i) {
    int c = i * 256 + tid, r = c >> 3, cc = c & 7, sc = cc ^ (r & 7);
    gl2lds16(Kg + (size_t)r * HD3_ + sc * 8, &Ks[0][0] + c * 8);
    gl2lds16(Vg + (size_t)r * T_ + sc * 8, &Vs[0][0] + c * 8);
  }

  f32x16 acc[2];
#pragma unroll
  for (int ni = 0; ni < 2; ++ni)
#pragma unroll
    for (int r = 0; r < 16; ++r) acc[ni][r] = 0.f;
  float mrun = -1e30f, lrun = 0.f;
  const int ktmax = 2 * qt + 2;

  for (int kt = 0; kt < ktmax; ++kt) {
    const int cur = kt & 1;
    const int kv0 = kt * 64;
    __syncthreads();
    if (kt + 1 < ktmax) {
      const int nkv = kv0 + 64;
#pragma unroll
      for (int i = 0; i < 2; ++i) {
        int c = i * 256 + tid, r = c >> 3, cc = c & 7, sc = cc ^ (r & 7);
        gl2lds16(Kg + (size_t)(nkv + r) * HD3_ + sc * 8, &Ks[cur ^ 1][0] + c * 8);
        gl2lds16(Vg + (size_t)r * T_ + nkv + sc * 8, &Vs[cur ^ 1][0] + c * 8);
      }
    }
    if (kv0 > qw0 + 31) continue;

    f32x16 st[2];
#pragma unroll
    for (int f = 0; f < 2; ++f)
#pragma unroll
      for (int r = 0; r < 16; ++r) st[f][r] = 0.f;
    __builtin_amdgcn_s_setprio(1);
#pragma unroll
    for (int f = 0; f < 2; ++f) {
      const int krow = f * 32 + ql;
      const int swzr = krow & 7;
#pragma unroll
      for (int s = 0; s < 4; ++s) {
        int ch = (2 * s + hi) ^ swzr;
        bf16x8 kfr = *(const bf16x8*)(&Ks[cur][0] + krow * 64 + ch * 8);
        st[f] = __builtin_amdgcn_mfma_f32_32x32x16_bf16(kfr, qf[s], st[f], 0, 0, 0);
      }
    }
    __builtin_amdgcn_s_setprio(0);

    if (kv0 + 63 > qw0) {
      const int qg = qw0 + ql;
#pragma unroll
      for (int f = 0; f < 2; ++f)
#pragma unroll
        for (int r = 0; r < 16; ++r) {
          int kg = kv0 + f * 32 + (r & 3) + 8 * (r >> 2) + 4 * hi;
          if (kg > qg) st[f][r] = -1e30f;
        }
    }

    float mt = st[0][0];
#pragma unroll
    for (int f = 0; f < 2; ++f)
#pragma unroll
      for (int r = 0; r < 16; ++r) mt = fmaxf(mt, st[f][r]);
    mt = fmaxf(mt, __shfl_xor(mt, 32, 64));
    if (!__all(mt - mrun <= 8.f)) {
      float mnew = fmaxf(mrun, mt);
      float corr = exp2f(mrun - mnew);
      lrun *= corr;
#pragma unroll
      for (int ni = 0; ni < 2; ++ni)
#pragma unroll
        for (int r = 0; r < 16; ++r) acc[ni][r] *= corr;
      mrun = mnew;
    }
    float sum = 0.f;
#pragma unroll
    for (int f = 0; f < 2; ++f)
#pragma unroll
      for (int r = 0; r < 16; ++r) {
        float p = exp2f(st[f][r] - mrun);
        st[f][r] = p;
        sum += p;
      }
    sum += __shfl_xor(sum, 32, 64);
    lrun += sum;

    __builtin_amdgcn_s_setprio(1);
#pragma unroll
    for (int s = 0; s < 4; ++s) {
      const int f = s >> 1, bse = (s & 1) * 8;
      unsigned b0 = cvtpk(st[f][bse + 0], st[f][bse + 1]);
      unsigned b1 = cvtpk(st[f][bse + 2], st[f][bse + 3]);
      unsigned a0 = cvtpk(st[f][bse + 4], st[f][bse + 5]);
      unsigned a1 = cvtpk(st[f][bse + 6], st[f][bse + 7]);
      asm volatile("v_permlane32_swap_b32 %0, %1" : "+v"(b0), "+v"(a0));
      asm volatile("v_permlane32_swap_b32 %0, %1" : "+v"(b1), "+v"(a1));
      union { unsigned u[4]; bf16x8 v; } pa;
      pa.u[0] = b0; pa.u[1] = b1; pa.u[2] = a0; pa.u[3] = a1;
#pragma unroll
      for (int ni = 0; ni < 2; ++ni) {
        int vrow = ni * 32 + ql;
        int ch = (2 * s + hi) ^ (vrow & 7);
        bf16x8 vf = *(const bf16x8*)(&Vs[cur][0] + vrow * 64 + ch * 8);
        acc[ni] = __builtin_amdgcn_mfma_f32_32x32x16_bf16(vf, pa.v, acc[ni], 0, 0, 0);
      }
    }
    __builtin_amdgcn_s_setprio(0);
  }

  const int q = q0 + w * 32 + ql;
  u16* Og = O + ((size_t)(b * T_ + q) * (H_ * D_) + h * 64);
  const float inv = 1.f / lrun;
#pragma unroll
  for (int ni = 0; ni < 2; ++ni)
#pragma unroll
    for (int rr = 0; rr < 8; ++rr) {
      const int r0 = rr * 2;
      const int d0 = ((r0 & 3) + 8 * (r0 >> 2)) + 4 * hi + ni * 32;
      unsigned pk = cvtpk(acc[ni][r0] * inv, acc[ni][r0 + 1] * inv);
      *(unsigned*)(Og + d0) = pk;
    }
}

// ---------------- launch ----------------
extern "C" void kernel_launch(void* const* d_in, const int* in_sizes, int n_in,
                              void* d_out, int out_size, void* d_ws, size_t ws_size,
                              hipStream_t stream) {
  const float* x  = (const float*)d_in[0];
  const float* Wq = (const float*)d_in[1];
  const float* Wk = (const float*)d_in[2];
  const float* Wv = (const float*)d_in[3];
  const float* Wc = (const float*)d_in[4];

  char* ws = (char*)d_ws;
  u16* xb  = (u16*)(ws);                    // 16.8 MB [8192][1024]
  u16* WT  = (u16*)(ws + 16777216);         // 6.3 MB  [3072][1024]
  u16* WcT = (u16*)(ws + 23068672);         // 2.1 MB  [1024][1024]
  u16* QKV = (u16*)(ws + 25165824);         // 50.3 MB [8192][3072]
  u16* Ob  = (u16*)(ws + 75497472);         // 16.8 MB [8192][1024]
  u16* VT  = xb;                            // reuse xb after proj GEMM
  float* out = (float*)d_out;

  const float QSCALE = 0.125f * 1.4426950408889634f;  // scale * log2(e)

  prep_x<<<2048, 256, 0, stream>>>(x, xb);
  prep_w<<<4096, 256, 0, stream>>>(Wq, Wk, Wv, Wc, WT, WcT);
  // QKV projection: M=8192, N=3072, K=1024 (Q columns pre-scaled)
  gemm8<3072, true><<<768, 512, 0, stream>>>(xb, WT, QKV, QSCALE);
  transpose_v<<<dim3(32, 64), 256, 0, stream>>>(QKV, VT);
  attn_kernel<<<dim3(1024), 256, 0, stream>>>(QKV, VT, Ob);
  // output projection: M=8192, N=1024, K=1024
  gemm8<1024, false><<<256, 512, 0, stream>>>(Ob, WcT, out, 1.0f);
}

// Round 4
// 260.206 us; speedup vs baseline: 1.7838x; 1.0254x over previous
//
#include <hip/hip_runtime.h>
#include <cstdint>
#include <cstddef>

typedef unsigned short u16;
typedef __bf16 bf16x8 __attribute__((ext_vector_type(8)));
typedef float f32x4 __attribute__((ext_vector_type(4)));
typedef float f32x16 __attribute__((ext_vector_type(16)));

#define B_ 4
#define T_ 2048
#define E_ 1024
#define H_ 16
#define D_ 64
#define HD3_ 3072
#define M_ (B_*T_)

#if __has_builtin(__builtin_amdgcn_exp2f)
#define EXP2F(x) __builtin_amdgcn_exp2f(x)
#else
#define EXP2F(x) exp2f(x)
#endif
#if __has_builtin(__builtin_amdgcn_rcpf)
#define RCPF(x) __builtin_amdgcn_rcpf(x)
#else
#define RCPF(x) (1.f/(x))
#endif

__device__ __forceinline__ u16 f2bf(float f) {
  union { float f; unsigned u; } v; v.f = f;
  unsigned r = v.u + 0x7FFFu + ((v.u >> 16) & 1u);
  return (u16)(r >> 16);
}

__device__ __forceinline__ unsigned cvtpk(float a, float b) {
  unsigned r;
  asm("v_cvt_pk_bf16_f32 %0, %1, %2" : "=v"(r) : "v"(a), "v"(b));
  return r;
}

__device__ __forceinline__ void gl2lds16(const u16* g, u16* l) {
  __builtin_amdgcn_global_load_lds(
      (const __attribute__((address_space(1))) unsigned int*)g,
      (__attribute__((address_space(3))) unsigned int*)l, 16, 0, 0);
}

// ---------------- prep: x -> bf16 ----------------
__global__ void prep_x(const float* __restrict__ x, u16* __restrict__ xb) {
  const long n4 = (long)(M_) * E_ / 4;
  for (long i = (long)blockIdx.x * blockDim.x + threadIdx.x; i < n4;
       i += (long)gridDim.x * blockDim.x) {
    float4 v = ((const float4*)x)[i];
    unsigned lo = (unsigned)f2bf(v.x) | ((unsigned)f2bf(v.y) << 16);
    unsigned hi = (unsigned)f2bf(v.z) | ((unsigned)f2bf(v.w) << 16);
    ((uint2*)xb)[i] = make_uint2(lo, hi);
  }
}

// ---------------- prep: weights -> bf16, transposed to [N][K] ----------------
__global__ void prep_w(const float* __restrict__ Wq, const float* __restrict__ Wk,
                       const float* __restrict__ Wv, const float* __restrict__ Wc,
                       u16* __restrict__ WT, u16* __restrict__ WcT) {
  const int total = HD3_ * E_ + E_ * E_;
  for (int i = blockIdx.x * blockDim.x + threadIdx.x; i < total;
       i += gridDim.x * blockDim.x) {
    if (i < HD3_ * E_) {
      int n = i >> 10, e = i & 1023;
      int mtx = n >> 10, hd = n & 1023, h = hd >> 6, d = hd & 63;
      const float* W = (mtx == 0) ? Wq : (mtx == 1) ? Wk : Wv;
      WT[i] = f2bf(W[((size_t)h * E_ + e) * D_ + d]);
    } else {
      int j = i - HD3_ * E_;
      int n = j >> 10, k = j & 1023;
      WcT[j] = f2bf(Wc[(size_t)k * E_ + n]);
    }
  }
}

// ---------------- 8-phase-style GEMM: C[M][N_] = A[M][1024] * Bt[N_][1024]^T ----------------
template<int N_, bool OUT_BF16>
__global__ __launch_bounds__(512, 2) void gemm8(
    const u16* __restrict__ A, const u16* __restrict__ Bt,
    void* __restrict__ Cv, float qscale)
{
  __shared__ u16 As[2][128 * 64];
  __shared__ u16 Bs[2][256 * 64];
  const int tid = threadIdx.x;
  const int lane = tid & 63, w = tid >> 6;
  const int wr = w >> 2, wc = w & 3;
  const int l15 = lane & 15, l4 = lane >> 4;

  const int gx = N_ / 256;
  const int lin = blockIdx.x;
  const int cpx = (gx * 64) >> 3;
  const int swz = (lin & 7) * cpx + (lin >> 3);
  const int bxi = swz % gx, byi = swz / gx;
  const size_t bm = (size_t)byi * 128, bn = (size_t)bxi * 256;
  const u16* Ag = A + bm * 1024;
  const u16* Bg = Bt + bn * 1024;

  auto stageA = [&](int b, int t, int i) {
    int idx = i * 512 + tid, r = idx >> 3, c = idx & 7;
    gl2lds16(Ag + (size_t)r * 1024 + t * 64 + ((c ^ (r & 7)) * 8), &As[b][idx * 8]);
  };
  auto stageB = [&](int b, int t, int i) {
    int idx = i * 512 + tid, r = idx >> 3, c = idx & 7;
    gl2lds16(Bg + (size_t)r * 1024 + t * 64 + ((c ^ (r & 7)) * 8), &Bs[b][idx * 8]);
  };

  int aoff[4][2], boff[4][2];
#pragma unroll
  for (int m = 0; m < 4; ++m) {
    int r = wr * 64 + m * 16 + l15;
#pragma unroll
    for (int s = 0; s < 2; ++s)
      aoff[m][s] = r * 64 + (((s * 4 + l4) ^ (r & 7)) * 8);
  }
#pragma unroll
  for (int n = 0; n < 4; ++n) {
    int r = wc * 64 + n * 16 + l15;
#pragma unroll
    for (int s = 0; s < 2; ++s)
      boff[n][s] = r * 64 + (((s * 4 + l4) ^ (r & 7)) * 8);
  }

  f32x4 acc[4][4] = {};

#pragma unroll
  for (int i = 0; i < 2; ++i) stageA(0, 0, i);
#pragma unroll
  for (int i = 0; i < 4; ++i) stageB(0, 0, i);
#pragma unroll
  for (int i = 0; i < 2; ++i) stageA(1, 1, i);
  asm volatile("s_waitcnt vmcnt(2)" ::: "memory");
  __builtin_amdgcn_s_barrier();

  for (int t = 0; t < 16; ++t) {
    const int cur = t & 1;
    bf16x8 af[4][2], bfv[4][2];
#pragma unroll
    for (int m = 0; m < 4; ++m)
#pragma unroll
      for (int s = 0; s < 2; ++s)
        af[m][s] = *(const bf16x8*)&As[cur][aoff[m][s]];
#pragma unroll
    for (int n = 0; n < 2; ++n)
#pragma unroll
      for (int s = 0; s < 2; ++s)
        bfv[n][s] = *(const bf16x8*)&Bs[cur][boff[n][s]];
    if (t + 1 < 16) {
      stageB(cur ^ 1, t + 1, 0);
      stageB(cur ^ 1, t + 1, 1);
      stageB(cur ^ 1, t + 1, 2);
    }
    __builtin_amdgcn_s_barrier();
    asm volatile("s_waitcnt lgkmcnt(0)" ::: "memory");
    __builtin_amdgcn_sched_barrier(0);
    __builtin_amdgcn_s_setprio(1);
#pragma unroll
    for (int m = 0; m < 4; ++m)
#pragma unroll
      for (int n = 0; n < 2; ++n)
#pragma unroll
        for (int s = 0; s < 2; ++s)
          acc[m][n] = __builtin_amdgcn_mfma_f32_16x16x32_bf16(
              af[m][s], bfv[n][s], acc[m][n], 0, 0, 0);
    __builtin_amdgcn_s_setprio(0);
    __builtin_amdgcn_s_barrier();

#pragma unroll
    for (int n = 2; n < 4; ++n)
#pragma unroll
      for (int s = 0; s < 2; ++s)
        bfv[n][s] = *(const bf16x8*)&Bs[cur][boff[n][s]];
    if (t + 1 < 16) stageB(cur ^ 1, t + 1, 3);
    if (t + 2 < 16) { stageA(cur, t + 2, 0); stageA(cur, t + 2, 1); }
    __builtin_amdgcn_s_barrier();
    asm volatile("s_waitcnt lgkmcnt(0)" ::: "memory");
    __builtin_amdgcn_sched_barrier(0);
    __builtin_amdgcn_s_setprio(1);
#pragma unroll
    for (int m = 0; m < 4; ++m)
#pragma unroll
      for (int n = 2; n < 4; ++n)
#pragma unroll
        for (int s = 0; s < 2; ++s)
          acc[m][n] = __builtin_amdgcn_mfma_f32_16x16x32_bf16(
              af[m][s], bfv[n][s], acc[m][n], 0, 0, 0);
    __builtin_amdgcn_s_setprio(0);
    if (t + 2 < 16)      asm volatile("s_waitcnt vmcnt(2)" ::: "memory");
    else if (t + 1 < 16) asm volatile("s_waitcnt vmcnt(0)" ::: "memory");
    __builtin_amdgcn_s_barrier();
  }

#pragma unroll
  for (int m = 0; m < 4; ++m)
#pragma unroll
    for (int n = 0; n < 4; ++n) {
      size_t row = bm + wr * 64 + m * 16 + l4 * 4;
      size_t col = bn + wc * 64 + n * 16 + l15;
      float sc = (col < 1024) ? qscale : 1.0f;
#pragma unroll
      for (int j = 0; j < 4; ++j) {
        if (OUT_BF16)
          ((u16*)Cv)[(row + j) * N_ + col] = f2bf(acc[m][n][j] * sc);
        else
          ((float*)Cv)[(row + j) * N_ + col] = acc[m][n][j];
      }
    }
}

// ---------------- V transpose: QKV V-part [B,T,H,D] -> VT[B*H][D][T] ----------------
__global__ __launch_bounds__(256) void transpose_v(const u16* __restrict__ QKV,
                                                   u16* __restrict__ VT) {
  const int bh = blockIdx.y, b = bh >> 4, h = bh & 15;
  const int t0 = blockIdx.x * 64;
  __shared__ u16 tile[64][72];
  const int tid = threadIdx.x;
  const u16* src = QKV + ((size_t)(b * T_ + t0) * HD3_ + 2048 + h * 64);
#pragma unroll
  for (int i = 0; i < 2; ++i) {
    int c = i * 256 + tid;
    int r = c >> 3, cc = (c & 7) * 8;
    uint4 v = *(const uint4*)(src + (size_t)r * HD3_ + cc);
    *(uint4*)&tile[r][cc] = v;
  }
  __syncthreads();
  u16* dst = VT + (size_t)bh * D_ * T_ + t0;
#pragma unroll
  for (int i = 0; i < 16; ++i) {
    int idx = i * 256 + tid;
    int d = idx >> 6, tl = idx & 63;
    dst[(size_t)d * T_ + tl] = tile[tl][d];
  }
}

// ---------------- flash attention (causal), swapped-QK 32x32 structure ----------------
// grid 1024; Latin-square qt mapping: blocks L, L+256, L+512, L+768 share a CU
// (stride-256 under standard dispatch) and get qts summing to 30 -> balanced.
// 4 blocks/CU co-resident (launch_bounds 256,4). Q pre-scaled by 0.125*log2(e).
__global__ __launch_bounds__(256, 4) void attn_kernel(
    const u16* __restrict__ QKV, const u16* __restrict__ VT,
    u16* __restrict__ O)
{
  __shared__ u16 Ks[2][4096];
  __shared__ u16 Vs[2][4096];
  const int L = blockIdx.x;
  const int bh = L & 63, b = bh >> 4, h = bh & 15;
  const int jj = L >> 8, gg = (L >> 6) & 3;
  const int qt = 4 * jj + ((gg + jj) & 3);
  const int q0 = qt * 128;
  const int tid = threadIdx.x, w = tid >> 6, lane = tid & 63;
  const int ql = lane & 31, hi = lane >> 5;
  const int qw0 = q0 + w * 32;

  const u16* Qg = QKV + ((size_t)(b * T_ + q0) * HD3_ + h * 64);
  const u16* Kg = QKV + ((size_t)(b * T_) * HD3_ + 1024 + h * 64);
  const u16* Vg = VT + (size_t)bh * (D_ * T_);

  // ---- stage Q [128][64], read per-wave Q frags
#pragma unroll
  for (int i = 0; i < 4; ++i) {
    int c = i * 256 + tid, r = c >> 3, cc = c & 7, sc = cc ^ (r & 7);
    gl2lds16(Qg + (size_t)r * HD3_ + sc * 8, &Ks[0][0] + c * 8);
  }
  __syncthreads();
  bf16x8 qf[4];
  {
    int qrow = w * 32 + ql;
#pragma unroll
    for (int s = 0; s < 4; ++s) {
      int ch = (2 * s + hi) ^ (qrow & 7);
      qf[s] = *(const bf16x8*)(&Ks[0][0] + qrow * 64 + ch * 8);
    }
  }
  __syncthreads();

  // ---- loop-invariant LDS frag offsets (K and V patterns are identical)
  int koff[2][4];
#pragma unroll
  for (int f = 0; f < 2; ++f) {
    int row = f * 32 + ql, swzr = row & 7;
#pragma unroll
    for (int s = 0; s < 4; ++s)
      koff[f][s] = row * 64 + (((2 * s + hi) ^ swzr) * 8);
  }

  // ---- running staging pointers (advance by one 64-tile per iteration)
  const int c0 = tid, c1 = 256 + tid;
  const int r0_ = c0 >> 3, sc0 = (c0 & 7) ^ (r0_ & 7);
  const int r1_ = c1 >> 3, sc1 = (c1 & 7) ^ (r1_ & 7);
  const int lo0 = c0 * 8, lo1 = c1 * 8;
  const u16* kp0 = Kg + (size_t)r0_ * HD3_ + sc0 * 8;
  const u16* kp1 = Kg + (size_t)r1_ * HD3_ + sc1 * 8;
  const u16* vp0 = Vg + (size_t)r0_ * T_ + sc0 * 8;
  const u16* vp1 = Vg + (size_t)r1_ * T_ + sc1 * 8;

  // stage tile 0 -> buf 0
  gl2lds16(kp0, &Ks[0][lo0]);
  gl2lds16(kp1, &Ks[0][lo1]);
  gl2lds16(vp0, &Vs[0][lo0]);
  gl2lds16(vp1, &Vs[0][lo1]);
  kp0 += 64 * HD3_; kp1 += 64 * HD3_;
  vp0 += 64; vp1 += 64;

  f32x16 acc[2];
#pragma unroll
  for (int ni = 0; ni < 2; ++ni)
#pragma unroll
    for (int r = 0; r < 16; ++r) acc[ni][r] = 0.f;
  float mrun = -1e30f, lrun = 0.f;
  const int ktmax = 2 * qt + 2;

  for (int kt = 0; kt < ktmax; ++kt) {
    const int cur = kt & 1;
    const int kv0 = kt * 64;
    __syncthreads();  // publish buf[cur] (drains vmcnt); protect buf[cur^1]
    if (kt + 1 < ktmax) {
      u16* kb = &Ks[cur ^ 1][0];
      u16* vb = &Vs[cur ^ 1][0];
      gl2lds16(kp0, kb + lo0);
      gl2lds16(kp1, kb + lo1);
      gl2lds16(vp0, vb + lo0);
      gl2lds16(vp1, vb + lo1);
      kp0 += 64 * HD3_; kp1 += 64 * HD3_;
      vp0 += 64; vp1 += 64;
    }
    if (kv0 > qw0 + 31) continue;
    const u16* kbase = &Ks[cur][0];
    const u16* vbase = &Vs[cur][0];

    // ---- S^T = K Q^T
    f32x16 st[2];
#pragma unroll
    for (int f = 0; f < 2; ++f)
#pragma unroll
      for (int r = 0; r < 16; ++r) st[f][r] = 0.f;
    __builtin_amdgcn_s_setprio(1);
#pragma unroll
    for (int f = 0; f < 2; ++f)
#pragma unroll
      for (int s = 0; s < 4; ++s) {
        bf16x8 kfr = *(const bf16x8*)(kbase + koff[f][s]);
        st[f] = __builtin_amdgcn_mfma_f32_32x32x16_bf16(kfr, qf[s], st[f], 0, 0, 0);
      }
    __builtin_amdgcn_s_setprio(0);

    // ---- causal mask (diagonal tiles only)
    if (kv0 + 63 > qw0) {
      const int qg = qw0 + ql;
#pragma unroll
      for (int f = 0; f < 2; ++f)
#pragma unroll
        for (int r = 0; r < 16; ++r) {
          int kg = kv0 + f * 32 + (r & 3) + 8 * (r >> 2) + 4 * hi;
          if (kg > qg) st[f][r] = -1e30f;
        }
    }

    // ---- tree max (depth 5) + defer-max THR=8
    float tr[16];
#pragma unroll
    for (int r = 0; r < 16; ++r) tr[r] = fmaxf(st[0][r], st[1][r]);
#pragma unroll
    for (int ss = 8; ss; ss >>= 1)
#pragma unroll
      for (int r = 0; r < 8; ++r)
        if (r < ss) tr[r] = fmaxf(tr[r], tr[r + ss]);
    float mt = fmaxf(tr[0], __shfl_xor(tr[0], 32, 64));
    if (!__all(mt - mrun <= 8.f)) {
      float mnew = fmaxf(mrun, mt);
      float corr = EXP2F(mrun - mnew);
      lrun *= corr;
#pragma unroll
      for (int ni = 0; ni < 2; ++ni)
#pragma unroll
        for (int r = 0; r < 16; ++r) acc[ni][r] *= corr;
      mrun = mnew;
    }

    // ---- exp (native v_exp_f32) + tree sum
#pragma unroll
    for (int f = 0; f < 2; ++f)
#pragma unroll
      for (int r = 0; r < 16; ++r) st[f][r] = EXP2F(st[f][r] - mrun);
#pragma unroll
    for (int r = 0; r < 16; ++r) tr[r] = st[0][r] + st[1][r];
#pragma unroll
    for (int ss = 8; ss; ss >>= 1)
#pragma unroll
      for (int r = 0; r < 8; ++r)
        if (r < ss) tr[r] += tr[r + ss];
    lrun += tr[0] + __shfl_xor(tr[0], 32, 64);

    // ---- P -> bf16 frags (cvt_pk + permlane32_swap), O^T += V^T P^T
    __builtin_amdgcn_s_setprio(1);
#pragma unroll
    for (int s = 0; s < 4; ++s) {
      const int f = s >> 1, bse = (s & 1) * 8;
      unsigned b0 = cvtpk(st[f][bse + 0], st[f][bse + 1]);
      unsigned b1 = cvtpk(st[f][bse + 2], st[f][bse + 3]);
      unsigned a0 = cvtpk(st[f][bse + 4], st[f][bse + 5]);
      unsigned a1 = cvtpk(st[f][bse + 6], st[f][bse + 7]);
      asm volatile("v_permlane32_swap_b32 %0, %1" : "+v"(b0), "+v"(a0));
      asm volatile("v_permlane32_swap_b32 %0, %1" : "+v"(b1), "+v"(a1));
      union { unsigned u[4]; bf16x8 v; } pa;
      pa.u[0] = b0; pa.u[1] = b1; pa.u[2] = a0; pa.u[3] = a1;
#pragma unroll
      for (int ni = 0; ni < 2; ++ni) {
        bf16x8 vf = *(const bf16x8*)(vbase + koff[ni][s]);
        acc[ni] = __builtin_amdgcn_mfma_f32_32x32x16_bf16(vf, pa.v, acc[ni], 0, 0, 0);
      }
    }
    __builtin_amdgcn_s_setprio(0);
  }

  // ---- epilogue: O[q][d] = acc^T / lrun, store bf16 pairs
  const int q = q0 + w * 32 + ql;
  u16* Og = O + ((size_t)(b * T_ + q) * (H_ * D_) + h * 64);
  const float inv = RCPF(lrun);
#pragma unroll
  for (int ni = 0; ni < 2; ++ni)
#pragma unroll
    for (int rr = 0; rr < 8; ++rr) {
      const int r0 = rr * 2;
      const int d0 = ((r0 & 3) + 8 * (r0 >> 2)) + 4 * hi + ni * 32;
      unsigned pk = cvtpk(acc[ni][r0] * inv, acc[ni][r0 + 1] * inv);
      *(unsigned*)(Og + d0) = pk;
    }
}

// ---------------- launch ----------------
extern "C" void kernel_launch(void* const* d_in, const int* in_sizes, int n_in,
                              void* d_out, int out_size, void* d_ws, size_t ws_size,
                              hipStream_t stream) {
  const float* x  = (const float*)d_in[0];
  const float* Wq = (const float*)d_in[1];
  const float* Wk = (const float*)d_in[2];
  const float* Wv = (const float*)d_in[3];
  const float* Wc = (const float*)d_in[4];

  char* ws = (char*)d_ws;
  u16* xb  = (u16*)(ws);                    // 16.8 MB [8192][1024]
  u16* WT  = (u16*)(ws + 16777216);         // 6.3 MB  [3072][1024]
  u16* WcT = (u16*)(ws + 23068672);         // 2.1 MB  [1024][1024]
  u16* QKV = (u16*)(ws + 25165824);         // 50.3 MB [8192][3072]
  u16* Ob  = (u16*)(ws + 75497472);         // 16.8 MB [8192][1024]
  u16* VT  = xb;                            // reuse xb after proj GEMM
  float* out = (float*)d_out;

  const float QSCALE = 0.125f * 1.4426950408889634f;  // scale * log2(e)

  prep_x<<<2048, 256, 0, stream>>>(x, xb);
  prep_w<<<4096, 256, 0, stream>>>(Wq, Wk, Wv, Wc, WT, WcT);
  gemm8<3072, true><<<768, 512, 0, stream>>>(xb, WT, QKV, QSCALE);
  transpose_v<<<dim3(32, 64), 256, 0, stream>>>(QKV, VT);
  attn_kernel<<<dim3(1024), 256, 0, stream>>>(QKV, VT, Ob);
  gemm8<1024, false><<<256, 512, 0, stream>>>(Ob, WcT, out, 1.0f);
}

// Round 7
// 253.332 us; speedup vs baseline: 1.8322x; 1.0271x over previous
//
#include <hip/hip_runtime.h>
#include <cstdint>
#include <cstddef>

typedef unsigned short u16;
typedef __bf16 bf16x8 __attribute__((ext_vector_type(8)));
typedef float f32x4 __attribute__((ext_vector_type(4)));
typedef float f32x16 __attribute__((ext_vector_type(16)));

#define B_ 4
#define T_ 2048
#define E_ 1024
#define H_ 16
#define D_ 64
#define HD3_ 3072
#define M_ (B_*T_)

#if __has_builtin(__builtin_amdgcn_exp2f)
#define EXP2F(x) __builtin_amdgcn_exp2f(x)
#else
#define EXP2F(x) exp2f(x)
#endif
#if __has_builtin(__builtin_amdgcn_rcpf)
#define RCPF(x) __builtin_amdgcn_rcpf(x)
#else
#define RCPF(x) (1.f/(x))
#endif

__device__ __forceinline__ u16 f2bf(float f) {
  union { float f; unsigned u; } v; v.f = f;
  unsigned r = v.u + 0x7FFFu + ((v.u >> 16) & 1u);
  return (u16)(r >> 16);
}

__device__ __forceinline__ unsigned cvtpk(float a, float b) {
  unsigned r;
  asm("v_cvt_pk_bf16_f32 %0, %1, %2" : "=v"(r) : "v"(a), "v"(b));
  return r;
}

__device__ __forceinline__ void gl2lds16(const u16* g, u16* l) {
  __builtin_amdgcn_global_load_lds(
      (const __attribute__((address_space(1))) unsigned int*)g,
      (__attribute__((address_space(3))) unsigned int*)l, 16, 0, 0);
}

// ---------------- prep: x -> bf16 ----------------
__global__ void prep_x(const float* __restrict__ x, u16* __restrict__ xb) {
  const long n4 = (long)(M_) * E_ / 4;
  for (long i = (long)blockIdx.x * blockDim.x + threadIdx.x; i < n4;
       i += (long)gridDim.x * blockDim.x) {
    float4 v = ((const float4*)x)[i];
    unsigned lo = (unsigned)f2bf(v.x) | ((unsigned)f2bf(v.y) << 16);
    unsigned hi = (unsigned)f2bf(v.z) | ((unsigned)f2bf(v.w) << 16);
    ((uint2*)xb)[i] = make_uint2(lo, hi);
  }
}

// ---------------- prep: weights -> bf16 transposed, via LDS 64x64 tile ----------------
// grid 1024: id<768 -> Wq/Wk/Wv part (48 (mtx,h) x 16 e-tiles); id>=768 -> Wc (256 tiles)
// QSCALE folded into Wq (mtx==0). Validated in round 5's first-pass check.
__global__ __launch_bounds__(256) void prep_w(
    const float* __restrict__ Wq, const float* __restrict__ Wk,
    const float* __restrict__ Wv, const float* __restrict__ Wc,
    u16* __restrict__ WT, u16* __restrict__ WcT, float qscale)
{
  __shared__ u16 tile[64][72];
  const int id = blockIdx.x;
  const int tid = threadIdx.x, lane = tid & 63;
  const float* src; int srcStride; u16* dst; float scale = 1.f;
  if (id < 768) {
    int mtxh = id >> 4, et = id & 15;
    int mtx = mtxh >> 4, h = mtxh & 15;
    const float* W = (mtx == 0) ? Wq : (mtx == 1) ? Wk : Wv;
    src = W + (size_t)h * 65536 + (size_t)(et * 64) * 64;   // rows=e (stride 64), cols=d
    srcStride = 64;
    dst = WT + (size_t)(mtx * 1024 + h * 64) * 1024 + et * 64;  // dst row=d, col=e
    if (mtx == 0) scale = qscale;
  } else {
    int j = id - 768;
    int kt = j >> 4, nt = j & 15;
    src = Wc + (size_t)(kt * 64) * 1024 + nt * 64;   // rows=k (stride 1024), cols=n
    srcStride = 1024;
    dst = WcT + (size_t)(nt * 64) * 1024 + kt * 64;  // dst row=n, col=k
  }
#pragma unroll
  for (int i = 0; i < 4; ++i) {
    int u = i * 256 + tid, r = u >> 4, c4 = (u & 15) * 4;
    float4 v = *(const float4*)(src + (size_t)r * srcStride + c4);
    *(uint2*)&tile[r][c4] = make_uint2(
        (unsigned)f2bf(v.x * scale) | ((unsigned)f2bf(v.y * scale) << 16),
        (unsigned)f2bf(v.z * scale) | ((unsigned)f2bf(v.w * scale) << 16));
  }
  __syncthreads();
#pragma unroll
  for (int i = 0; i < 2; ++i) {
    int grp = i * 4 + (tid >> 6);
    u16 tmp[8];
#pragma unroll
    for (int j = 0; j < 8; ++j) tmp[j] = tile[grp * 8 + j][lane];
    *(uint4*)(dst + (size_t)lane * 1024 + grp * 8) = *(uint4*)tmp;
  }
}

// ---------------- GEMM (round-4 structure, race-screened twice): ----------------
// C[M][N_] = A[M][1024] * Bt[N_][1024]^T. tile 128x256, BK=64, 512 thr = 8 waves
// (2M x 4N, wave-tile 64x64). LDS 96KB, chunk-XOR swizzle, counted-vmcnt pipeline.
template<int N_, bool OUT_BF16>
__global__ __launch_bounds__(512, 2) void gemm8(
    const u16* __restrict__ A, const u16* __restrict__ Bt, void* __restrict__ Cv)
{
  __shared__ u16 As[2][128 * 64];
  __shared__ u16 Bs[2][256 * 64];
  const int tid = threadIdx.x;
  const int lane = tid & 63, w = tid >> 6;
  const int wr = w >> 2, wc = w & 3;
  const int l15 = lane & 15, l4 = lane >> 4;

  const int gx = N_ / 256;
  const int lin = blockIdx.x;
  const int cpx = (gx * 64) >> 3;
  const int swz = (lin & 7) * cpx + (lin >> 3);
  const int bxi = swz % gx, byi = swz / gx;
  const size_t bm = (size_t)byi * 128, bn = (size_t)bxi * 256;
  const u16* Ag = A + bm * 1024;
  const u16* Bg = Bt + bn * 1024;

  auto stageA = [&](int b, int t, int i) {
    int idx = i * 512 + tid, r = idx >> 3, c = idx & 7;
    gl2lds16(Ag + (size_t)r * 1024 + t * 64 + ((c ^ (r & 7)) * 8), &As[b][idx * 8]);
  };
  auto stageB = [&](int b, int t, int i) {
    int idx = i * 512 + tid, r = idx >> 3, c = idx & 7;
    gl2lds16(Bg + (size_t)r * 1024 + t * 64 + ((c ^ (r & 7)) * 8), &Bs[b][idx * 8]);
  };

  int aoff[4][2], boff[4][2];
#pragma unroll
  for (int m = 0; m < 4; ++m) {
    int r = wr * 64 + m * 16 + l15;
#pragma unroll
    for (int s = 0; s < 2; ++s)
      aoff[m][s] = r * 64 + (((s * 4 + l4) ^ (r & 7)) * 8);
  }
#pragma unroll
  for (int n = 0; n < 4; ++n) {
    int r = wc * 64 + n * 16 + l15;
#pragma unroll
    for (int s = 0; s < 2; ++s)
      boff[n][s] = r * 64 + (((s * 4 + l4) ^ (r & 7)) * 8);
  }

  f32x4 acc[4][4] = {};

#pragma unroll
  for (int i = 0; i < 2; ++i) stageA(0, 0, i);
#pragma unroll
  for (int i = 0; i < 4; ++i) stageB(0, 0, i);
#pragma unroll
  for (int i = 0; i < 2; ++i) stageA(1, 1, i);
  asm volatile("s_waitcnt vmcnt(2)" ::: "memory");
  __builtin_amdgcn_s_barrier();

  for (int t = 0; t < 16; ++t) {
    const int cur = t & 1;
    bf16x8 af[4][2], bfv[4][2];
#pragma unroll
    for (int m = 0; m < 4; ++m)
#pragma unroll
      for (int s = 0; s < 2; ++s)
        af[m][s] = *(const bf16x8*)&As[cur][aoff[m][s]];
#pragma unroll
    for (int n = 0; n < 2; ++n)
#pragma unroll
      for (int s = 0; s < 2; ++s)
        bfv[n][s] = *(const bf16x8*)&Bs[cur][boff[n][s]];
    if (t + 1 < 16) {
      stageB(cur ^ 1, t + 1, 0);
      stageB(cur ^ 1, t + 1, 1);
      stageB(cur ^ 1, t + 1, 2);
    }
    __builtin_amdgcn_s_barrier();
    asm volatile("s_waitcnt lgkmcnt(0)" ::: "memory");
    __builtin_amdgcn_sched_barrier(0);
    __builtin_amdgcn_s_setprio(1);
#pragma unroll
    for (int m = 0; m < 4; ++m)
#pragma unroll
      for (int n = 0; n < 2; ++n)
#pragma unroll
        for (int s = 0; s < 2; ++s)
          acc[m][n] = __builtin_amdgcn_mfma_f32_16x16x32_bf16(
              af[m][s], bfv[n][s], acc[m][n], 0, 0, 0);
    __builtin_amdgcn_s_setprio(0);
    __builtin_amdgcn_s_barrier();

#pragma unroll
    for (int n = 2; n < 4; ++n)
#pragma unroll
      for (int s = 0; s < 2; ++s)
        bfv[n][s] = *(const bf16x8*)&Bs[cur][boff[n][s]];
    if (t + 1 < 16) stageB(cur ^ 1, t + 1, 3);
    if (t + 2 < 16) { stageA(cur, t + 2, 0); stageA(cur, t + 2, 1); }
    __builtin_amdgcn_s_barrier();
    asm volatile("s_waitcnt lgkmcnt(0)" ::: "memory");
    __builtin_amdgcn_sched_barrier(0);
    __builtin_amdgcn_s_setprio(1);
#pragma unroll
    for (int m = 0; m < 4; ++m)
#pragma unroll
      for (int n = 2; n < 4; ++n)
#pragma unroll
        for (int s = 0; s < 2; ++s)
          acc[m][n] = __builtin_amdgcn_mfma_f32_16x16x32_bf16(
              af[m][s], bfv[n][s], acc[m][n], 0, 0, 0);
    __builtin_amdgcn_s_setprio(0);
    if (t + 2 < 16)      asm volatile("s_waitcnt vmcnt(2)" ::: "memory");
    else if (t + 1 < 16) asm volatile("s_waitcnt vmcnt(0)" ::: "memory");
    __builtin_amdgcn_s_barrier();
  }

#pragma unroll
  for (int m = 0; m < 4; ++m)
#pragma unroll
    for (int n = 0; n < 4; ++n) {
      size_t row = bm + wr * 64 + m * 16 + l4 * 4;
      size_t col = bn + wc * 64 + n * 16 + l15;
#pragma unroll
      for (int j = 0; j < 4; ++j) {
        if (OUT_BF16)
          ((u16*)Cv)[(row + j) * N_ + col] = f2bf(acc[m][n][j]);
        else
          ((float*)Cv)[(row + j) * N_ + col] = acc[m][n][j];
      }
    }
}

// ---------------- V transpose: QKV V-part [B,T,H,D] -> VT[B*H][D][T] ----------------
__global__ __launch_bounds__(256) void transpose_v(const u16* __restrict__ QKV,
                                                   u16* __restrict__ VT) {
  const int bh = blockIdx.y, b = bh >> 4, h = bh & 15;
  const int t0 = blockIdx.x * 64;
  __shared__ u16 tile[64][72];
  const int tid = threadIdx.x, lane = tid & 63;
  const u16* src = QKV + ((size_t)(b * T_ + t0) * HD3_ + 2048 + h * 64);
#pragma unroll
  for (int i = 0; i < 2; ++i) {
    int c = i * 256 + tid, r = c >> 3, cc = (c & 7) * 8;
    *(uint4*)&tile[r][cc] = *(const uint4*)(src + (size_t)r * HD3_ + cc);
  }
  __syncthreads();
  u16* dst = VT + (size_t)bh * (D_ * T_) + t0;
#pragma unroll
  for (int i = 0; i < 2; ++i) {
    int grp = i * 4 + (tid >> 6);
    u16 tmp[8];
#pragma unroll
    for (int j = 0; j < 8; ++j) tmp[j] = tile[grp * 8 + j][lane];
    *(uint4*)(dst + (size_t)lane * T_ + grp * 8) = *(uint4*)tmp;
  }
}

// ---------------- flash attention (causal), swapped-QK 32x32 structure ----------------
__global__ __launch_bounds__(256, 4) void attn_kernel(
    const u16* __restrict__ QKV, const u16* __restrict__ VT,
    u16* __restrict__ O)
{
  __shared__ u16 Ks[2][4096];
  __shared__ u16 Vs[2][4096];
  const int L = blockIdx.x;
  const int bh = L & 63, b = bh >> 4, h = bh & 15;
  const int jj = L >> 8, gg = (L >> 6) & 3;
  const int qt = 4 * jj + ((gg + jj) & 3);
  const int q0 = qt * 128;
  const int tid = threadIdx.x, w = tid >> 6, lane = tid & 63;
  const int ql = lane & 31, hi = lane >> 5;
  const int qw0 = q0 + w * 32;

  const u16* Qg = QKV + ((size_t)(b * T_ + q0) * HD3_ + h * 64);
  const u16* Kg = QKV + ((size_t)(b * T_) * HD3_ + 1024 + h * 64);
  const u16* Vg = VT + (size_t)bh * (D_ * T_);

#pragma unroll
  for (int i = 0; i < 4; ++i) {
    int c = i * 256 + tid, r = c >> 3, cc = c & 7, sc = cc ^ (r & 7);
    gl2lds16(Qg + (size_t)r * HD3_ + sc * 8, &Ks[0][0] + c * 8);
  }
  __syncthreads();
  bf16x8 qf[4];
  {
    int qrow = w * 32 + ql;
#pragma unroll
    for (int s = 0; s < 4; ++s) {
      int ch = (2 * s + hi) ^ (qrow & 7);
      qf[s] = *(const bf16x8*)(&Ks[0][0] + qrow * 64 + ch * 8);
    }
  }
  __syncthreads();

  int koff[2][4];
#pragma unroll
  for (int f = 0; f < 2; ++f) {
    int row = f * 32 + ql, swzr = row & 7;
#pragma unroll
    for (int s = 0; s < 4; ++s)
      koff[f][s] = row * 64 + (((2 * s + hi) ^ swzr) * 8);
  }

  const int c0 = tid, c1 = 256 + tid;
  const int r0_ = c0 >> 3, sc0 = (c0 & 7) ^ (r0_ & 7);
  const int r1_ = c1 >> 3, sc1 = (c1 & 7) ^ (r1_ & 7);
  const int lo0 = c0 * 8, lo1 = c1 * 8;
  const u16* kp0 = Kg + (size_t)r0_ * HD3_ + sc0 * 8;
  const u16* kp1 = Kg + (size_t)r1_ * HD3_ + sc1 * 8;
  const u16* vp0 = Vg + (size_t)r0_ * T_ + sc0 * 8;
  const u16* vp1 = Vg + (size_t)r1_ * T_ + sc1 * 8;

  gl2lds16(kp0, &Ks[0][lo0]);
  gl2lds16(kp1, &Ks[0][lo1]);
  gl2lds16(vp0, &Vs[0][lo0]);
  gl2lds16(vp1, &Vs[0][lo1]);
  kp0 += 64 * HD3_; kp1 += 64 * HD3_;
  vp0 += 64; vp1 += 64;

  f32x16 acc[2];
#pragma unroll
  for (int ni = 0; ni < 2; ++ni)
#pragma unroll
    for (int r = 0; r < 16; ++r) acc[ni][r] = 0.f;
  float mrun = -1e30f, lrun = 0.f;
  const int ktmax = 2 * qt + 2;

  for (int kt = 0; kt < ktmax; ++kt) {
    const int cur = kt & 1;
    const int kv0 = kt * 64;
    __syncthreads();
    if (kt + 1 < ktmax) {
      u16* kb = &Ks[cur ^ 1][0];
      u16* vb = &Vs[cur ^ 1][0];
      gl2lds16(kp0, kb + lo0);
      gl2lds16(kp1, kb + lo1);
      gl2lds16(vp0, vb + lo0);
      gl2lds16(vp1, vb + lo1);
      kp0 += 64 * HD3_; kp1 += 64 * HD3_;
      vp0 += 64; vp1 += 64;
    }
    if (kv0 > qw0 + 31) continue;
    const u16* kbase = &Ks[cur][0];
    const u16* vbase = &Vs[cur][0];

    f32x16 st[2];
#pragma unroll
    for (int f = 0; f < 2; ++f)
#pragma unroll
      for (int r = 0; r < 16; ++r) st[f][r] = 0.f;
    __builtin_amdgcn_s_setprio(1);
#pragma unroll
    for (int f = 0; f < 2; ++f)
#pragma unroll
      for (int s = 0; s < 4; ++s) {
        bf16x8 kfr = *(const bf16x8*)(kbase + koff[f][s]);
        st[f] = __builtin_amdgcn_mfma_f32_32x32x16_bf16(kfr, qf[s], st[f], 0, 0, 0);
      }
    __builtin_amdgcn_s_setprio(0);

    if (kv0 + 63 > qw0) {
      const int qg = qw0 + ql;
#pragma unroll
      for (int f = 0; f < 2; ++f)
#pragma unroll
        for (int r = 0; r < 16; ++r) {
          int kg = kv0 + f * 32 + (r & 3) + 8 * (r >> 2) + 4 * hi;
          if (kg > qg) st[f][r] = -1e30f;
        }
    }

    float tr[16];
#pragma unroll
    for (int r = 0; r < 16; ++r) tr[r] = fmaxf(st[0][r], st[1][r]);
#pragma unroll
    for (int ss = 8; ss; ss >>= 1)
#pragma unroll
      for (int r = 0; r < 8; ++r)
        if (r < ss) tr[r] = fmaxf(tr[r], tr[r + ss]);
    float mt = fmaxf(tr[0], __shfl_xor(tr[0], 32, 64));
    if (!__all(mt - mrun <= 8.f)) {
      float mnew = fmaxf(mrun, mt);
      float corr = EXP2F(mrun - mnew);
      lrun *= corr;
#pragma unroll
      for (int ni = 0; ni < 2; ++ni)
#pragma unroll
        for (int r = 0; r < 16; ++r) acc[ni][r] *= corr;
      mrun = mnew;
    }
#pragma unroll
    for (int f = 0; f < 2; ++f)
#pragma unroll
      for (int r = 0; r < 16; ++r) st[f][r] = EXP2F(st[f][r] - mrun);
#pragma unroll
    for (int r = 0; r < 16; ++r) tr[r] = st[0][r] + st[1][r];
#pragma unroll
    for (int ss = 8; ss; ss >>= 1)
#pragma unroll
      for (int r = 0; r < 8; ++r)
        if (r < ss) tr[r] += tr[r + ss];
    lrun += tr[0] + __shfl_xor(tr[0], 32, 64);

    __builtin_amdgcn_s_setprio(1);
#pragma unroll
    for (int s = 0; s < 4; ++s) {
      const int f = s >> 1, bse = (s & 1) * 8;
      unsigned b0 = cvtpk(st[f][bse + 0], st[f][bse + 1]);
      unsigned b1 = cvtpk(st[f][bse + 2], st[f][bse + 3]);
      unsigned a0 = cvtpk(st[f][bse + 4], st[f][bse + 5]);
      unsigned a1 = cvtpk(st[f][bse + 6], st[f][bse + 7]);
      asm volatile("v_permlane32_swap_b32 %0, %1" : "+v"(b0), "+v"(a0));
      asm volatile("v_permlane32_swap_b32 %0, %1" : "+v"(b1), "+v"(a1));
      union { unsigned u[4]; bf16x8 v; } pa;
      pa.u[0] = b0; pa.u[1] = b1; pa.u[2] = a0; pa.u[3] = a1;
#pragma unroll
      for (int ni = 0; ni < 2; ++ni) {
        bf16x8 vf = *(const bf16x8*)(vbase + koff[ni][s]);
        acc[ni] = __builtin_amdgcn_mfma_f32_32x32x16_bf16(vf, pa.v, acc[ni], 0, 0, 0);
      }
    }
    __builtin_amdgcn_s_setprio(0);
  }

  const int q = q0 + w * 32 + ql;
  u16* Og = O + ((size_t)(b * T_ + q) * (H_ * D_) + h * 64);
  const float inv = RCPF(lrun);
#pragma unroll
  for (int ni = 0; ni < 2; ++ni)
#pragma unroll
    for (int rr = 0; rr < 8; ++rr) {
      const int r0 = rr * 2;
      const int d0 = ((r0 & 3) + 8 * (r0 >> 2)) + 4 * hi + ni * 32;
      unsigned pk = cvtpk(acc[ni][r0] * inv, acc[ni][r0 + 1] * inv);
      *(unsigned*)(Og + d0) = pk;
    }
}

// ---------------- launch ----------------
extern "C" void kernel_launch(void* const* d_in, const int* in_sizes, int n_in,
                              void* d_out, int out_size, void* d_ws, size_t ws_size,
                              hipStream_t stream) {
  const float* x  = (const float*)d_in[0];
  const float* Wq = (const float*)d_in[1];
  const float* Wk = (const float*)d_in[2];
  const float* Wv = (const float*)d_in[3];
  const float* Wc = (const float*)d_in[4];

  char* ws = (char*)d_ws;
  u16* xb  = (u16*)(ws);                    // 16.8 MB [8192][1024]
  u16* WT  = (u16*)(ws + 16777216);         // 6.3 MB  [3072][1024]
  u16* WcT = (u16*)(ws + 23068672);         // 2.1 MB  [1024][1024]
  u16* QKV = (u16*)(ws + 25165824);         // 50.3 MB [8192][3072]
  u16* Ob  = (u16*)(ws + 75497472);         // 16.8 MB [8192][1024]
  u16* VT  = xb;                            // reuse xb after proj GEMM
  float* out = (float*)d_out;

  const float QSCALE = 0.125f * 1.4426950408889634f;  // scale * log2(e), folded into Wq

  prep_x<<<2048, 256, 0, stream>>>(x, xb);
  prep_w<<<1024, 256, 0, stream>>>(Wq, Wk, Wv, Wc, WT, WcT, QSCALE);
  gemm8<3072, true><<<768, 512, 0, stream>>>(xb, WT, QKV);
  transpose_v<<<dim3(32, 64), 256, 0, stream>>>(QKV, VT);
  attn_kernel<<<dim3(1024), 256, 0, stream>>>(QKV, VT, Ob);
  gemm8<1024, false><<<256, 512, 0, stream>>>(Ob, WcT, out);
}